// Round 1
// baseline (674.120 us; speedup 1.0000x reference)
//
#include <hip/hip_runtime.h>
#include <math.h>

// SelfAttentionRouter: B=16384, CAPS=32, FEAT=256, fp32.
// out[b,j] = sum_i x[b,i,j] * (softmax_i(scores)[b,i] + bias[i,j])
// scores[b,i] = (1/16) * sum_j x[b,i,j] * colsum[b,j],  colsum[b,j] = sum_k x[b,k,j]
//
// One block per batch element. 256 threads = 4 waves.
// Wave w owns caps [8w, 8w+8); lane f = t&63 owns features [4f, 4f+4) (float4).
// Single pass over the input tile (32 KiB), held in registers (8 x float4).

constexpr int CAPS = 32;
constexpr int FEAT = 256;

__global__ __launch_bounds__(256, 4)
void router_kernel(const float* __restrict__ inp,
                   const float* __restrict__ bias,
                   float* __restrict__ out) {
    const int b    = blockIdx.x;
    const int t    = threadIdx.x;
    const int f    = t & 63;   // feature group (4 consecutive floats)
    const int w    = t >> 6;   // wave id; owns caps [8w, 8w+8)

    const float4* inp4  = reinterpret_cast<const float4*>(inp + (size_t)b * CAPS * FEAT);
    const float4* bias4 = reinterpret_cast<const float4*>(bias);

    __shared__ float4 red_lds[4][64];    // cross-wave reduce buffer (csum, then out)
    __shared__ float  scores_lds[CAPS];
    __shared__ float  sm_lds[CAPS];

    // ---- load: 8 caps x 4 features per thread (coalesced float4, 16B/lane) ----
    float4 x[8];
    #pragma unroll
    for (int il = 0; il < 8; ++il) {
        const int i = w * 8 + il;
        x[il] = inp4[i * (FEAT / 4) + f];
    }

    // ---- colsum (sum over caps): per-wave partial, then cross-wave via LDS ----
    float4 pc = x[0];
    #pragma unroll
    for (int il = 1; il < 8; ++il) {
        pc.x += x[il].x; pc.y += x[il].y; pc.z += x[il].z; pc.w += x[il].w;
    }
    red_lds[w][f] = pc;
    __syncthreads();
    float4 cs = red_lds[0][f];
    {
        const float4 a = red_lds[1][f];
        const float4 c = red_lds[2][f];
        const float4 d = red_lds[3][f];
        cs.x += a.x + c.x + d.x;
        cs.y += a.y + c.y + d.y;
        cs.z += a.z + c.z + d.z;
        cs.w += a.w + c.w + d.w;
    }

    // ---- scores: p[il] = dot4(x[il], cs), wave-reduce over 64 lanes ----
    float p[8];
    #pragma unroll
    for (int il = 0; il < 8; ++il) {
        p[il] = x[il].x * cs.x + x[il].y * cs.y + x[il].z * cs.z + x[il].w * cs.w;
    }
    #pragma unroll
    for (int step = 1; step < 64; step <<= 1) {
        #pragma unroll
        for (int il = 0; il < 8; ++il)
            p[il] += __shfl_xor(p[il], step, 64);
    }
    if (f == 0) {
        #pragma unroll
        for (int il = 0; il < 8; ++il)
            scores_lds[w * 8 + il] = p[il];
    }
    __syncthreads();

    // ---- softmax over 32 caps (threads 0..31, shuffles stay within lanes 0..31) ----
    if (t < CAPS) {
        const float s = scores_lds[t] * 0.0625f;   // 1/sqrt(256)
        float m = s;
        #pragma unroll
        for (int step = 1; step < 32; step <<= 1)
            m = fmaxf(m, __shfl_xor(m, step, 64));
        const float e = __expf(s - m);
        float tot = e;
        #pragma unroll
        for (int step = 1; step < 32; step <<= 1)
            tot += __shfl_xor(tot, step, 64);
        sm_lds[t] = e / tot;
    }
    __syncthreads();

    // ---- out partial: sum over this wave's 8 caps of x * (sm[i] + bias[i,:]) ----
    float4 acc = make_float4(0.f, 0.f, 0.f, 0.f);
    #pragma unroll
    for (int il = 0; il < 8; ++il) {
        const int i = w * 8 + il;
        const float4 bv = bias4[i * (FEAT / 4) + f];
        const float  s  = sm_lds[i];
        acc.x += x[il].x * (s + bv.x);
        acc.y += x[il].y * (s + bv.y);
        acc.z += x[il].z * (s + bv.z);
        acc.w += x[il].w * (s + bv.w);
    }

    // ---- cross-wave output reduce (red_lds reuse is safe: two barriers since last read) ----
    red_lds[w][f] = acc;
    __syncthreads();
    if (w == 0) {
        const float4 a0 = red_lds[0][f];
        const float4 a1 = red_lds[1][f];
        const float4 a2 = red_lds[2][f];
        const float4 a3 = red_lds[3][f];
        float4 o;
        o.x = a0.x + a1.x + a2.x + a3.x;
        o.y = a0.y + a1.y + a2.y + a3.y;
        o.z = a0.z + a1.z + a2.z + a3.z;
        o.w = a0.w + a1.w + a2.w + a3.w;
        reinterpret_cast<float4*>(out + (size_t)b * FEAT)[f] = o;
    }
}

extern "C" void kernel_launch(void* const* d_in, const int* in_sizes, int n_in,
                              void* d_out, int out_size, void* d_ws, size_t ws_size,
                              hipStream_t stream) {
    const float* inp  = reinterpret_cast<const float*>(d_in[0]);
    const float* bias = reinterpret_cast<const float*>(d_in[1]);
    float* out        = reinterpret_cast<float*>(d_out);

    const int batch = in_sizes[0] / (CAPS * FEAT);   // 16384
    router_kernel<<<batch, 256, 0, stream>>>(inp, bias, out);
}